// Round 6
// baseline (714.424 us; speedup 1.0000x reference)
//
#include <hip/hip_runtime.h>

// 2-layer GCN. Bucket-grouped edges (no node-level CSR), LDS accumulators.
// Pipeline:
//  A k_hist     : per-block LDS hist over NB dst-buckets (bucket = dst>>8)
//  B k_bscan    : per-bucket exclusive scan over the 256 blocks
//  C k_cscan    : exclusive scan of bucket totals -> bucket bases
//  D k_dscatter : scatter packed (src<<8|dst&255) into bucket-grouped array
//  E k_degdinv  : per-bucket node hist -> dinv = rsqrt(deg+1)
//  F k_gemm1    : pp = (x@W1)*dinv[row], f32 compute, bf16 store
//  G k_fused1   : block=bucket, acc[256][64] f32 in LDS (64KB); stream grouped,
//                 LDS-atomic gathered bf16 rows; finalize h=relu(dinv*acc+b1),
//                 qp=(h.W2)*dinv  -- no csr, no global atomics
//  H k_fused2   : block=bucket, a2[256] LDS; out = dinv*(a2+qp[self])+b2
//
// NOTE (gfx950): __shfl = ds_bpermute; reading from an exec-masked-off source
// lane is UNDEFINED. All shuffles below are issued with full exec (uniform
// lane args); divergence only gates the consuming loads/atomics.

#define NBLK 256          // blocks in hist/scatter (k_bscan scans exactly 256)

__device__ __forceinline__ float bf2f(unsigned short u) {
    union { unsigned int i; float f; } v; v.i = ((unsigned int)u) << 16; return v.f;
}
__device__ __forceinline__ unsigned short f2bf(float f) {
    union { float f; unsigned int i; } v; v.f = f;
    unsigned int r = (v.i + 0x7fffu + ((v.i >> 16) & 1u)) >> 16;
    return (unsigned short)r;
}

// A: per-block histogram of dst buckets
__global__ __launch_bounds__(256) void k_hist(const int* __restrict__ dst, int E, int chunk,
                                              int NB, int* __restrict__ bh) {
    __shared__ int h[512];
    int blk = blockIdx.x, t = threadIdx.x;
    h[t] = 0; h[t + 256] = 0;
    __syncthreads();
    int e0 = blk * chunk, e1 = min(E, e0 + chunk);
    for (int e = e0 + t; e < e1; e += 256) atomicAdd(&h[dst[e] >> 8], 1);
    __syncthreads();
    for (int k = t; k < NB; k += 256) bh[blk * NB + k] = h[k];
}

// B: per-bucket exclusive scan over NBLK block counts; btot[k] = bucket total
__global__ __launch_bounds__(256) void k_bscan(int* __restrict__ bh, int NB,
                                               int* __restrict__ btot) {
    __shared__ int s[256];
    int k = blockIdx.x, t = threadIdx.x;
    int v = bh[t * NB + k];
    s[t] = v;
    __syncthreads();
    for (int off = 1; off < 256; off <<= 1) {
        int u = (t >= off) ? s[t - off] : 0;
        __syncthreads();
        s[t] += u;
        __syncthreads();
    }
    bh[t * NB + k] = s[t] - v;
    if (t == 255) btot[k] = s[255];
}

// C: exclusive scan of bucket totals (NB <= 512)
__global__ __launch_bounds__(512) void k_cscan(const int* __restrict__ btot, int NB,
                                               int* __restrict__ bbase) {
    __shared__ int s[512];
    int t = threadIdx.x;
    int v = (t < NB) ? btot[t] : 0;
    s[t] = v;
    __syncthreads();
    for (int off = 1; off < 512; off <<= 1) {
        int u = (t >= off) ? s[t - off] : 0;
        __syncthreads();
        s[t] += u;
        __syncthreads();
    }
    if (t < NB) bbase[t] = s[t] - v;
}

// D: scatter packed records into bucket-grouped order
__global__ __launch_bounds__(256) void k_dscatter(const int* __restrict__ src,
                                                  const int* __restrict__ dst, int E, int chunk,
                                                  const int* __restrict__ bh,
                                                  const int* __restrict__ bbase, int NB,
                                                  unsigned int* __restrict__ grouped) {
    __shared__ int cur[512];
    int blk = blockIdx.x, t = threadIdx.x;
    for (int k = t; k < NB; k += 256) cur[k] = bbase[k] + bh[blk * NB + k];
    __syncthreads();
    int e0 = blk * chunk, e1 = min(E, e0 + chunk);
    for (int e = e0 + t; e < e1; e += 256) {
        int d = dst[e];
        int pos = atomicAdd(&cur[d >> 8], 1);
        grouped[pos] = ((unsigned int)src[e] << 8) | (unsigned int)(d & 255);
    }
}

// E: per-bucket node degree -> dinv
__global__ __launch_bounds__(256) void k_degdinv(const unsigned int* __restrict__ grouped,
                                                 const int* __restrict__ bbase,
                                                 const int* __restrict__ btot, int N,
                                                 float* __restrict__ dinv) {
    __shared__ int h[256];
    int k = blockIdx.x, t = threadIdx.x;
    h[t] = 0;
    __syncthreads();
    int base = bbase[k], cnt = btot[k];
    for (int i = t; i < cnt; i += 256) atomicAdd(&h[grouped[base + i] & 255u], 1);
    __syncthreads();
    int node = (k << 8) + t;
    if (node < N) dinv[node] = rsqrtf((float)h[t] + 1.0f);
}

// F: pp[r][c] = (sum_k x[r][k]*W1[k][c]) * dinv[r], f32 compute, bf16 store
__global__ __launch_bounds__(256) void k_gemm1(
    const float* __restrict__ x, const float* __restrict__ W1,
    const float* __restrict__ dinv, unsigned short* __restrict__ ppb, int N)
{
    __shared__ float xs[64][132];
    __shared__ float ws[128][64];
    int tid = threadIdx.x;
    int row0 = blockIdx.x * 64;
    {
        const float4* w4 = (const float4*)W1;
        float4* s4 = (float4*)&ws[0][0];
        #pragma unroll
        for (int i = 0; i < 8; i++) s4[tid + 256 * i] = w4[tid + 256 * i];
    }
    {
        int maxr = N - row0; if (maxr > 64) maxr = 64;
        const float4* x4 = (const float4*)(x + (size_t)row0 * 128);
        int n4 = maxr * 32;
        for (int i = tid; i < n4; i += 256) {
            int r = i >> 5, c = i & 31;
            *(float4*)&xs[r][c * 4] = x4[i];
        }
    }
    __syncthreads();
    int c0 = (tid & 15) * 4;
    int r0 = (tid >> 4) * 4;
    float acc[4][4] = {};
    for (int kk = 0; kk < 128; kk += 4) {
        float xv[4][4], wv[4][4];
        #pragma unroll
        for (int i = 0; i < 4; i++) *(float4*)xv[i] = *(const float4*)&xs[r0 + i][kk];
        #pragma unroll
        for (int t = 0; t < 4; t++) *(float4*)wv[t] = *(const float4*)&ws[kk + t][c0];
        #pragma unroll
        for (int i = 0; i < 4; i++)
            #pragma unroll
            for (int j = 0; j < 4; j++)
                acc[i][j] += xv[i][0] * wv[0][j] + xv[i][1] * wv[1][j]
                           + xv[i][2] * wv[2][j] + xv[i][3] * wv[3][j];
    }
    #pragma unroll
    for (int i = 0; i < 4; i++) {
        int r = row0 + r0 + i;
        if (r < N) {
            float d = dinv[r];
            ushort4 o;
            o.x = f2bf(acc[i][0] * d);
            o.y = f2bf(acc[i][1] * d);
            o.z = f2bf(acc[i][2] * d);
            o.w = f2bf(acc[i][3] * d);
            *(ushort4*)&ppb[(size_t)r * 64 + c0] = o;
        }
    }
}

// G: block = bucket. acc[d][(c+d)&63] += pp[src][c]; finalize -> qp.
__global__ __launch_bounds__(1024) void k_fused1(const unsigned int* __restrict__ grouped,
                                                 const int* __restrict__ bbase,
                                                 const int* __restrict__ btot,
                                                 const unsigned short* __restrict__ ppb,
                                                 const float* __restrict__ dinv,
                                                 const float* __restrict__ b1,
                                                 const float* __restrict__ W2,
                                                 float* __restrict__ qp, int N) {
    __shared__ float acc[256 * 64];   // exactly 64 KB
    int k = blockIdx.x, t = threadIdx.x;
    {   // zero
        float4 z = make_float4(0.f, 0.f, 0.f, 0.f);
        float4* a4 = (float4*)acc;
        #pragma unroll
        for (int i = 0; i < 4; i++) a4[t + 1024 * i] = z;
    }
    __syncthreads();
    int base = bbase[k], cnt = btot[k];
    int lane = t & 63, wid = t >> 6;
    int hl = lane & 31, half = lane >> 5;
    // accumulate: each wave takes 64-record chunks, 2 records per inner step.
    // ALL shuffles issued with full exec and wave-uniform lane indices.
    for (int i0 = wid * 64; i0 < cnt; i0 += 16 * 64) {
        int m = cnt - i0; if (m > 64) m = 64;
        unsigned int idx = (lane < m) ? grouped[base + i0 + lane] : 0u;
        for (int kk = 0; kk < m; kk += 2) {
            int kk1 = (kk + 1 < m) ? kk + 1 : kk;        // wave-uniform
            unsigned int p0 = __shfl(idx, kk, 64);       // full-exec shuffle
            unsigned int p1 = __shfl(idx, kk1, 64);      // full-exec shuffle
            unsigned int p = half ? p1 : p0;
            bool act = (!half) || (kk + 1 < m);          // suppress odd-tail dup
            if (act) {
                int s = (int)(p >> 8);
                int d = (int)(p & 255u);
                unsigned int v = *(const unsigned int*)&ppb[(size_t)s * 64 + 2 * hl];
                float f0 = bf2f((unsigned short)(v & 0xffffu));
                float f1 = bf2f((unsigned short)(v >> 16));
                int c0 = (2 * hl + d) & 63;
                int c1 = (2 * hl + 1 + d) & 63;
                atomicAdd(&acc[d * 64 + c0], f0);
                atomicAdd(&acc[d * 64 + c1], f1);
            }
        }
    }
    __syncthreads();
    // finalize: wave wid handles nodes [wid*16, wid*16+16)
    float w2 = W2[lane];
    float bb = b1[lane];
    for (int d = wid * 16; d < wid * 16 + 16; d++) {
        int node = (k << 8) + d;
        if (node >= N) break;
        float a = acc[d * 64 + ((lane + d) & 63)];
        a += bf2f(ppb[(size_t)node * 64 + lane]);   // self-loop term
        float di = dinv[node];
        float h = fmaxf(di * a + bb, 0.0f);
        float v = h * w2;
        #pragma unroll
        for (int m = 32; m > 0; m >>= 1) v += __shfl_xor(v, m, 64);
        if (lane == 0) qp[node] = v * di;
    }
}

// H: block = bucket. a2[dst] += qp[src]; out = dinv*(a2+qp[self]) + b2
__global__ __launch_bounds__(256) void k_fused2(const unsigned int* __restrict__ grouped,
                                                const int* __restrict__ bbase,
                                                const int* __restrict__ btot,
                                                const float* __restrict__ qp,
                                                const float* __restrict__ dinv,
                                                const float* __restrict__ b2,
                                                float* __restrict__ out, int N) {
    __shared__ float a2[256];
    int k = blockIdx.x, t = threadIdx.x;
    a2[t] = 0.0f;
    __syncthreads();
    int base = bbase[k], cnt = btot[k];
    for (int i = t; i < cnt; i += 256) {
        unsigned int p = grouped[base + i];
        atomicAdd(&a2[p & 255u], qp[p >> 8]);
    }
    __syncthreads();
    int node = (k << 8) + t;
    if (node < N) out[node] = dinv[node] * (a2[t] + qp[node]) + b2[0];
}

extern "C" void kernel_launch(void* const* d_in, const int* in_sizes, int n_in,
                              void* d_out, int out_size, void* d_ws, size_t ws_size,
                              hipStream_t stream) {
    const float* x  = (const float*)d_in[0];
    const int*   ei = (const int*)d_in[1];
    const float* W1 = (const float*)d_in[2];
    const float* b1 = (const float*)d_in[3];
    const float* W2 = (const float*)d_in[4];
    const float* b2 = (const float*)d_in[5];
    float* out = (float*)d_out;

    int N = in_sizes[0] / 128;
    int E = in_sizes[1] / 2;
    const int* src = ei;
    const int* dst = ei + E;
    int NB = (N + 255) >> 8;          // dst buckets (<=512 for N<=131072)
    int chunk = (E + NBLK - 1) / NBLK;

    size_t Np = ((size_t)N + 255) & ~(size_t)255;
    size_t Ep = ((size_t)E + 255) & ~(size_t)255;
    char* w = (char*)d_ws;
    int* bh      = (int*)w;            w += (size_t)NBLK * 512 * 4;   // [blk][bucket]
    int* btot    = (int*)w;            w += 512 * 4;
    int* bbase   = (int*)w;            w += 512 * 4;
    unsigned int* grouped = (unsigned int*)w;  w += Ep * 4;
    float* dinv  = (float*)w;          w += Np * 4;
    unsigned short* ppb = (unsigned short*)w;  w += Np * 64 * 2;
    float* qp    = (float*)w;          /* Np*4 */

    k_hist<<<NBLK, 256, 0, stream>>>(dst, E, chunk, NB, bh);
    k_bscan<<<NB, 256, 0, stream>>>(bh, NB, btot);
    k_cscan<<<1, 512, 0, stream>>>(btot, NB, bbase);
    k_dscatter<<<NBLK, 256, 0, stream>>>(src, dst, E, chunk, bh, bbase, NB, grouped);
    k_degdinv<<<NB, 256, 0, stream>>>(grouped, bbase, btot, N, dinv);
    k_gemm1<<<(N + 63) / 64, 256, 0, stream>>>(x, W1, dinv, ppb, N);
    k_fused1<<<NB, 1024, 0, stream>>>(grouped, bbase, btot, ppb, dinv, b1, W2, qp, N);
    k_fused2<<<NB, 256, 0, stream>>>(grouped, bbase, btot, qp, dinv, b2, out, N);
}

// Round 7
// 209.656 us; speedup vs baseline: 3.4076x; 3.4076x over previous
//
#include <hip/hip_runtime.h>

// 2-layer GCN. R4 pipeline (LDS-multisplit CSR build, bf16 pp) with an
// MLP-unrolled fused1 (4 gathers in flight). NO per-edge LDS atomics (R6
// lesson: LDS-atomic accumulate was 10x slower than register accumulate).
// Pipeline:
//  A k_hist     : per-block LDS hist over NB dst-buckets (bucket = dst>>8)
//  B k_bscan    : per-bucket exclusive scan over the 256 blocks
//  C k_cscan    : exclusive scan of bucket totals -> bucket bases
//  D k_dscatter : scatter packed (src<<8|dst&255) into bucket-grouped array
//  E k_bfill    : per-bucket node hist+scan -> offs/dinv; csr via LDS staging
//  F k_gemm1    : pp = (x@W1)*dinv[row], f32 compute, bf16 store
//  G k_fused1   : wave/node, 8 records/step (4 loads in flight);
//                 h=relu(dinv*acc+b1); qp=(h.W2)*dinv
//  H k_fused2   : thread/node: out = dinv*(qp[self]+sum qp[csr]) + b2
//
// gfx950 NOTE: __shfl = ds_bpermute; source lane must be exec-active.
// All shuffles below run full-exec with wave-uniform lane indices.

#define NBLK 256
#define MAXB 8192

__device__ __forceinline__ float bf2f(unsigned short u) {
    union { unsigned int i; float f; } v; v.i = ((unsigned int)u) << 16; return v.f;
}
__device__ __forceinline__ unsigned short f2bf(float f) {
    union { float f; unsigned int i; } v; v.f = f;
    unsigned int r = (v.i + 0x7fffu + ((v.i >> 16) & 1u)) >> 16;
    return (unsigned short)r;
}

// A: per-block histogram of dst buckets
__global__ __launch_bounds__(256) void k_hist(const int* __restrict__ dst, int E, int chunk,
                                              int NB, int* __restrict__ bh) {
    __shared__ int h[512];
    int blk = blockIdx.x, t = threadIdx.x;
    h[t] = 0; h[t + 256] = 0;
    __syncthreads();
    int e0 = blk * chunk, e1 = min(E, e0 + chunk);
    for (int e = e0 + t; e < e1; e += 256) atomicAdd(&h[dst[e] >> 8], 1);
    __syncthreads();
    for (int k = t; k < NB; k += 256) bh[blk * NB + k] = h[k];
}

// B: per-bucket exclusive scan over NBLK block counts
__global__ __launch_bounds__(256) void k_bscan(int* __restrict__ bh, int NB,
                                               int* __restrict__ btot) {
    __shared__ int s[256];
    int k = blockIdx.x, t = threadIdx.x;
    int v = bh[t * NB + k];
    s[t] = v;
    __syncthreads();
    for (int off = 1; off < 256; off <<= 1) {
        int u = (t >= off) ? s[t - off] : 0;
        __syncthreads();
        s[t] += u;
        __syncthreads();
    }
    bh[t * NB + k] = s[t] - v;
    if (t == 255) btot[k] = s[255];
}

// C: exclusive scan of bucket totals (NB <= 512)
__global__ __launch_bounds__(512) void k_cscan(const int* __restrict__ btot, int NB, int E,
                                               int* __restrict__ bbase, int* __restrict__ offs,
                                               int N) {
    __shared__ int s[512];
    int t = threadIdx.x;
    int v = (t < NB) ? btot[t] : 0;
    s[t] = v;
    __syncthreads();
    for (int off = 1; off < 512; off <<= 1) {
        int u = (t >= off) ? s[t - off] : 0;
        __syncthreads();
        s[t] += u;
        __syncthreads();
    }
    if (t < NB) bbase[t] = s[t] - v;
    if (t == 0) offs[N] = E;
}

// D: scatter packed records into bucket-grouped order (LDS cursors)
__global__ __launch_bounds__(256) void k_dscatter(const int* __restrict__ src,
                                                  const int* __restrict__ dst, int E, int chunk,
                                                  const int* __restrict__ bh,
                                                  const int* __restrict__ bbase, int NB,
                                                  unsigned int* __restrict__ grouped) {
    __shared__ int cur[512];
    int blk = blockIdx.x, t = threadIdx.x;
    for (int k = t; k < NB; k += 256) cur[k] = bbase[k] + bh[blk * NB + k];
    __syncthreads();
    int e0 = blk * chunk, e1 = min(E, e0 + chunk);
    for (int e = e0 + t; e < e1; e += 256) {
        int d = dst[e];
        int pos = atomicAdd(&cur[d >> 8], 1);
        grouped[pos] = ((unsigned int)src[e] << 8) | (unsigned int)(d & 255);
    }
}

// E: per-bucket node hist/scan -> offs, dinv; csr fill via LDS staging
__global__ __launch_bounds__(256) void k_bfill(const unsigned int* __restrict__ grouped,
                                               const int* __restrict__ bbase,
                                               const int* __restrict__ btot, int N,
                                               int* __restrict__ offs, int* __restrict__ csr,
                                               float* __restrict__ dinv) {
    __shared__ int hist[256], pfx[256], cur[256];
    __shared__ int stage[MAXB];
    int k = blockIdx.x, t = threadIdx.x;
    int base = bbase[k], cnt = btot[k];
    hist[t] = 0;
    __syncthreads();
    for (int i = t; i < cnt; i += 256) atomicAdd(&hist[grouped[base + i] & 255u], 1);
    __syncthreads();
    int v = hist[t];
    pfx[t] = v;
    __syncthreads();
    for (int off = 1; off < 256; off <<= 1) {
        int u = (t >= off) ? pfx[t - off] : 0;
        __syncthreads();
        pfx[t] += u;
        __syncthreads();
    }
    int excl = pfx[t] - v;
    cur[t] = excl;
    int node = (k << 8) + t;
    if (node < N) {
        offs[node] = base + excl;
        dinv[node] = rsqrtf((float)v + 1.0f);
    }
    __syncthreads();
    if (cnt <= MAXB) {
        for (int i = t; i < cnt; i += 256) {
            unsigned int p = grouped[base + i];
            int pos = atomicAdd(&cur[p & 255u], 1);
            stage[pos] = (int)(p >> 8);
        }
        __syncthreads();
        for (int i = t; i < cnt; i += 256) csr[base + i] = stage[i];
    } else {
        for (int i = t; i < cnt; i += 256) {
            unsigned int p = grouped[base + i];
            int pos = atomicAdd(&cur[p & 255u], 1);
            csr[base + pos] = (int)(p >> 8);
        }
    }
}

// F: pp[r][c] = (sum_k x[r][k]*W1[k][c]) * dinv[r], f32 compute, bf16 store
__global__ __launch_bounds__(256) void k_gemm1(
    const float* __restrict__ x, const float* __restrict__ W1,
    const float* __restrict__ dinv, unsigned short* __restrict__ ppb, int N)
{
    __shared__ float xs[64][132];
    __shared__ float ws[128][64];
    int tid = threadIdx.x;
    int row0 = blockIdx.x * 64;
    {
        const float4* w4 = (const float4*)W1;
        float4* s4 = (float4*)&ws[0][0];
        #pragma unroll
        for (int i = 0; i < 8; i++) s4[tid + 256 * i] = w4[tid + 256 * i];
    }
    {
        int maxr = N - row0; if (maxr > 64) maxr = 64;
        const float4* x4 = (const float4*)(x + (size_t)row0 * 128);
        int n4 = maxr * 32;
        for (int i = tid; i < n4; i += 256) {
            int r = i >> 5, c = i & 31;
            *(float4*)&xs[r][c * 4] = x4[i];
        }
    }
    __syncthreads();
    int c0 = (tid & 15) * 4;
    int r0 = (tid >> 4) * 4;
    float acc[4][4] = {};
    for (int kk = 0; kk < 128; kk += 4) {
        float xv[4][4], wv[4][4];
        #pragma unroll
        for (int i = 0; i < 4; i++) *(float4*)xv[i] = *(const float4*)&xs[r0 + i][kk];
        #pragma unroll
        for (int t = 0; t < 4; t++) *(float4*)wv[t] = *(const float4*)&ws[kk + t][c0];
        #pragma unroll
        for (int i = 0; i < 4; i++)
            #pragma unroll
            for (int j = 0; j < 4; j++)
                acc[i][j] += xv[i][0] * wv[0][j] + xv[i][1] * wv[1][j]
                           + xv[i][2] * wv[2][j] + xv[i][3] * wv[3][j];
    }
    #pragma unroll
    for (int i = 0; i < 4; i++) {
        int r = row0 + r0 + i;
        if (r < N) {
            float d = dinv[r];
            ushort4 o;
            o.x = f2bf(acc[i][0] * d);
            o.y = f2bf(acc[i][1] * d);
            o.z = f2bf(acc[i][2] * d);
            o.w = f2bf(acc[i][3] * d);
            *(ushort4*)&ppb[(size_t)r * 64 + c0] = o;
        }
    }
}

// G: wave/node; 8 records per step = 4 independent half-wave gathers in flight.
__global__ void k_fused1(const int* __restrict__ offs, const int* __restrict__ csr,
                         const unsigned short* __restrict__ ppb,
                         const float* __restrict__ dinv, const float* __restrict__ b1,
                         const float* __restrict__ W2, float* __restrict__ qp, int N) {
    int t = blockIdx.x * blockDim.x + threadIdx.x;
    int lane = t & 63;
    int half = lane >> 5;
    int hl = lane & 31;
    int node = t >> 6;
    int nstride = (gridDim.x * blockDim.x) >> 6;
    float w2a = W2[2 * hl], w2b = W2[2 * hl + 1];
    float ba = b1[2 * hl], bb = b1[2 * hl + 1];
    for (; node < N; node += nstride) {
        int start = offs[node], end = offs[node + 1];
        float acca = 0.0f, accb = 0.0f;
        if (half == 0) {  // self-loop term counted once
            unsigned int v = *(const unsigned int*)&ppb[(size_t)node * 64 + 2 * hl];
            acca = bf2f((unsigned short)v);
            accb = bf2f((unsigned short)(v >> 16));
        }
        for (int j0 = start; j0 < end; j0 += 64) {
            int jj = j0 + lane;
            int idx = (jj < end) ? csr[jj] : 0;
            int m = end - j0; if (m > 64) m = 64;
            for (int kk = 0; kk < m; kk += 8) {   // 8 records, 4 loads in flight
                int sidx[4]; bool act[4];
                #pragma unroll
                for (int q = 0; q < 4; q++) {
                    int ka = kk + 2 * q, kb = ka + 1;
                    int kac = (ka < m) ? ka : m - 1;     // wave-uniform clamp
                    int kbc = (kb < m) ? kb : m - 1;
                    int s0 = __shfl(idx, kac, 64);       // full-exec shuffles
                    int s1 = __shfl(idx, kbc, 64);
                    sidx[q] = half ? s1 : s0;
                    act[q] = half ? (kb < m) : (ka < m);
                }
                unsigned int v[4];
                #pragma unroll
                for (int q = 0; q < 4; q++)
                    if (act[q]) v[q] = *(const unsigned int*)&ppb[(size_t)sidx[q] * 64 + 2 * hl];
                #pragma unroll
                for (int q = 0; q < 4; q++)
                    if (act[q]) {
                        acca += bf2f((unsigned short)(v[q] & 0xffffu));
                        accb += bf2f((unsigned short)(v[q] >> 16));
                    }
            }
        }
        acca += __shfl_xor(acca, 32, 64);
        accb += __shfl_xor(accb, 32, 64);
        float di = dinv[node];
        float ha = fmaxf(di * acca + ba, 0.0f);
        float hb = fmaxf(di * accb + bb, 0.0f);
        float v = ha * w2a + hb * w2b;
        #pragma unroll
        for (int mm = 16; mm > 0; mm >>= 1) v += __shfl_xor(v, mm, 64);
        if (lane == 0) qp[node] = v * di;
    }
}

// H: out = dinv*(qp[self] + sum qp[csr]) + b2
__global__ void k_fused2(const int* __restrict__ offs, const int* __restrict__ csr,
                         const float* __restrict__ qp, const float* __restrict__ dinv,
                         const float* __restrict__ b2, float* __restrict__ out, int N) {
    int i = blockIdx.x * blockDim.x + threadIdx.x;
    if (i < N) {
        int start = offs[i], end = offs[i + 1];
        float s = qp[i];
        for (int j = start; j < end; j++) s += qp[csr[j]];
        out[i] = dinv[i] * s + b2[0];
    }
}

extern "C" void kernel_launch(void* const* d_in, const int* in_sizes, int n_in,
                              void* d_out, int out_size, void* d_ws, size_t ws_size,
                              hipStream_t stream) {
    const float* x  = (const float*)d_in[0];
    const int*   ei = (const int*)d_in[1];
    const float* W1 = (const float*)d_in[2];
    const float* b1 = (const float*)d_in[3];
    const float* W2 = (const float*)d_in[4];
    const float* b2 = (const float*)d_in[5];
    float* out = (float*)d_out;

    int N = in_sizes[0] / 128;
    int E = in_sizes[1] / 2;
    const int* src = ei;
    const int* dst = ei + E;
    int NB = (N + 255) >> 8;
    int chunk = (E + NBLK - 1) / NBLK;

    size_t Np = ((size_t)N + 255) & ~(size_t)255;
    size_t Ep = ((size_t)E + 255) & ~(size_t)255;
    char* w = (char*)d_ws;
    int* bh      = (int*)w;            w += (size_t)NBLK * 512 * 4;
    int* btot    = (int*)w;            w += 512 * 4;
    int* bbase   = (int*)w;            w += 512 * 4;
    unsigned int* grouped = (unsigned int*)w;  w += Ep * 4;
    int* offs    = (int*)w;            w += (Np + 256) * 4;
    int* csr     = (int*)w;            w += Ep * 4;
    float* dinv  = (float*)w;          w += Np * 4;
    unsigned short* ppb = (unsigned short*)w;  w += Np * 64 * 2;
    float* qp    = (float*)w;          /* Np*4 */

    k_hist<<<NBLK, 256, 0, stream>>>(dst, E, chunk, NB, bh);
    k_bscan<<<NB, 256, 0, stream>>>(bh, NB, btot);
    k_cscan<<<1, 512, 0, stream>>>(btot, NB, E, bbase, offs, N);
    k_dscatter<<<NBLK, 256, 0, stream>>>(src, dst, E, chunk, bh, bbase, NB, grouped);
    k_bfill<<<NB, 256, 0, stream>>>(grouped, bbase, btot, N, offs, csr, dinv);
    k_gemm1<<<(N + 63) / 64, 256, 0, stream>>>(x, W1, dinv, ppb, N);
    k_fused1<<<2048, 256, 0, stream>>>(offs, csr, ppb, dinv, b1, W2, qp, N);
    k_fused2<<<(N + 255) / 256, 256, 0, stream>>>(offs, csr, qp, dinv, b2, out, N);
}

// Round 8
// 197.505 us; speedup vs baseline: 3.6172x; 1.0615x over previous
//
#include <hip/hip_runtime.h>

// 2-layer GCN. LDS-multisplit CSR build + bf16 MFMA gemm1 + ILP-unrolled fused1.
// Pipeline:
//  P k_packB    : W1 -> bf16 B-fragments in mfma_16x16x32 per-lane order (16 KB)
//  A k_hist     : per-block LDS hist over NB dst-buckets (bucket = dst>>8)
//  B k_bscan    : per-bucket exclusive scan over the 256 blocks
//  C k_cscan    : exclusive scan of bucket totals -> bucket bases
//  D k_dscatter : scatter packed (src<<8|dst&255) into bucket-grouped array
//  E k_bfill    : per-bucket node hist+scan -> offs/dinv; csr via LDS staging
//  F k_gemm1m   : pp = (x@W1)*dinv[row] via v_mfma_f32_16x16x32_bf16, bf16 store
//  G k_fused1   : wave/node, 8 records/step (4 gathers in flight);
//                 h=relu(dinv*acc+b1); qp=(h.W2)*dinv
//  H k_fused2   : thread/node: out = dinv*(qp[self]+sum qp[csr]) + b2
//
// gfx950 NOTES: __shfl = ds_bpermute (source lane must be exec-active; all
// shuffles run full-exec with wave-uniform lane args). No per-edge LDS atomics
// (R6: 10x slower than register accumulation).
// MFMA 16x16x32 bf16 layouts: A row=l&15,k=(l>>4)*8+j; B col=l&15,k=(l>>4)*8+j;
// C/D col=lane&15,row=(lane>>4)*4+reg (m89-verified).

#define NBLK 256
#define MAXB 8192

typedef __attribute__((ext_vector_type(8))) short bf16x8;
typedef __attribute__((ext_vector_type(4))) float f32x4;

__device__ __forceinline__ float bf2f(unsigned short u) {
    union { unsigned int i; float f; } v; v.i = ((unsigned int)u) << 16; return v.f;
}
__device__ __forceinline__ unsigned short f2bf(float f) {
    union { float f; unsigned int i; } v; v.f = f;
    unsigned int r = (v.i + 0x7fffu + ((v.i >> 16) & 1u)) >> 16;
    return (unsigned short)r;
}

// P: pack W1 (f32 [128][64]) into bf16 B-fragments.
// Bfrag[(((nt*4+ks)*64+lane)*8+j)] = bf16(W1[(ks*32+(lane>>4)*8+j)*64 + nt*16+(lane&15)])
__global__ __launch_bounds__(256) void k_packB(const float* __restrict__ W1,
                                               unsigned short* __restrict__ Bfrag) {
    for (int i = threadIdx.x; i < 8192; i += 256) {
        int j    = i & 7;
        int lane = (i >> 3) & 63;
        int ks   = (i >> 9) & 3;
        int nt   = i >> 11;
        int k = ks * 32 + ((lane >> 4) << 3) + j;
        int n = nt * 16 + (lane & 15);
        Bfrag[i] = f2bf(W1[k * 64 + n]);
    }
}

// A: per-block histogram of dst buckets
__global__ __launch_bounds__(256) void k_hist(const int* __restrict__ dst, int E, int chunk,
                                              int NB, int* __restrict__ bh) {
    __shared__ int h[512];
    int blk = blockIdx.x, t = threadIdx.x;
    h[t] = 0; h[t + 256] = 0;
    __syncthreads();
    int e0 = blk * chunk, e1 = min(E, e0 + chunk);
    for (int e = e0 + t; e < e1; e += 256) atomicAdd(&h[dst[e] >> 8], 1);
    __syncthreads();
    for (int k = t; k < NB; k += 256) bh[blk * NB + k] = h[k];
}

// B: per-bucket exclusive scan over NBLK block counts
__global__ __launch_bounds__(256) void k_bscan(int* __restrict__ bh, int NB,
                                               int* __restrict__ btot) {
    __shared__ int s[256];
    int k = blockIdx.x, t = threadIdx.x;
    int v = bh[t * NB + k];
    s[t] = v;
    __syncthreads();
    for (int off = 1; off < 256; off <<= 1) {
        int u = (t >= off) ? s[t - off] : 0;
        __syncthreads();
        s[t] += u;
        __syncthreads();
    }
    bh[t * NB + k] = s[t] - v;
    if (t == 255) btot[k] = s[255];
}

// C: exclusive scan of bucket totals (NB <= 512)
__global__ __launch_bounds__(512) void k_cscan(const int* __restrict__ btot, int NB, int E,
                                               int* __restrict__ bbase, int* __restrict__ offs,
                                               int N) {
    __shared__ int s[512];
    int t = threadIdx.x;
    int v = (t < NB) ? btot[t] : 0;
    s[t] = v;
    __syncthreads();
    for (int off = 1; off < 512; off <<= 1) {
        int u = (t >= off) ? s[t - off] : 0;
        __syncthreads();
        s[t] += u;
        __syncthreads();
    }
    if (t < NB) bbase[t] = s[t] - v;
    if (t == 0) offs[N] = E;
}

// D: scatter packed records into bucket-grouped order (LDS cursors)
__global__ __launch_bounds__(256) void k_dscatter(const int* __restrict__ src,
                                                  const int* __restrict__ dst, int E, int chunk,
                                                  const int* __restrict__ bh,
                                                  const int* __restrict__ bbase, int NB,
                                                  unsigned int* __restrict__ grouped) {
    __shared__ int cur[512];
    int blk = blockIdx.x, t = threadIdx.x;
    for (int k = t; k < NB; k += 256) cur[k] = bbase[k] + bh[blk * NB + k];
    __syncthreads();
    int e0 = blk * chunk, e1 = min(E, e0 + chunk);
    for (int e = e0 + t; e < e1; e += 256) {
        int d = dst[e];
        int pos = atomicAdd(&cur[d >> 8], 1);
        grouped[pos] = ((unsigned int)src[e] << 8) | (unsigned int)(d & 255);
    }
}

// E: per-bucket node hist/scan -> offs, dinv; csr fill via LDS staging
__global__ __launch_bounds__(256) void k_bfill(const unsigned int* __restrict__ grouped,
                                               const int* __restrict__ bbase,
                                               const int* __restrict__ btot, int N,
                                               int* __restrict__ offs, int* __restrict__ csr,
                                               float* __restrict__ dinv) {
    __shared__ int hist[256], pfx[256], cur[256];
    __shared__ int stage[MAXB];
    int k = blockIdx.x, t = threadIdx.x;
    int base = bbase[k], cnt = btot[k];
    hist[t] = 0;
    __syncthreads();
    for (int i = t; i < cnt; i += 256) atomicAdd(&hist[grouped[base + i] & 255u], 1);
    __syncthreads();
    int v = hist[t];
    pfx[t] = v;
    __syncthreads();
    for (int off = 1; off < 256; off <<= 1) {
        int u = (t >= off) ? pfx[t - off] : 0;
        __syncthreads();
        pfx[t] += u;
        __syncthreads();
    }
    int excl = pfx[t] - v;
    cur[t] = excl;
    int node = (k << 8) + t;
    if (node < N) {
        offs[node] = base + excl;
        dinv[node] = rsqrtf((float)v + 1.0f);
    }
    __syncthreads();
    if (cnt <= MAXB) {
        for (int i = t; i < cnt; i += 256) {
            unsigned int p = grouped[base + i];
            int pos = atomicAdd(&cur[p & 255u], 1);
            stage[pos] = (int)(p >> 8);
        }
        __syncthreads();
        for (int i = t; i < cnt; i += 256) csr[base + i] = stage[i];
    } else {
        for (int i = t; i < cnt; i += 256) {
            unsigned int p = grouped[base + i];
            int pos = atomicAdd(&cur[p & 255u], 1);
            csr[base + pos] = (int)(p >> 8);
        }
    }
}

// F: MFMA gemm1. Block = 4 waves x 16 rows = 64 rows, all 64 cols. No LDS.
__global__ __launch_bounds__(256) void k_gemm1m(
    const float* __restrict__ x, const unsigned short* __restrict__ Bfrag,
    const float* __restrict__ dinv, unsigned short* __restrict__ ppb, int N)
{
    int lane = threadIdx.x & 63;
    int wid = threadIdx.x >> 6;
    int r0 = blockIdx.x * 64 + wid * 16;
    int arow = r0 + (lane & 15);
    if (arow > N - 1) arow = N - 1;              // clamp (stores guarded)
    const float* xrow = x + (size_t)arow * 128 + ((lane >> 4) << 3);

    f32x4 acc0 = {0.f, 0.f, 0.f, 0.f};
    f32x4 acc1 = {0.f, 0.f, 0.f, 0.f};
    f32x4 acc2 = {0.f, 0.f, 0.f, 0.f};
    f32x4 acc3 = {0.f, 0.f, 0.f, 0.f};

    #pragma unroll
    for (int ks = 0; ks < 4; ks++) {
        // A fragment: 8 consecutive f32 -> 8 bf16
        float4 a0 = *(const float4*)(xrow + ks * 32);
        float4 a1 = *(const float4*)(xrow + ks * 32 + 4);
        bf16x8 a;
        a[0] = (short)f2bf(a0.x); a[1] = (short)f2bf(a0.y);
        a[2] = (short)f2bf(a0.z); a[3] = (short)f2bf(a0.w);
        a[4] = (short)f2bf(a1.x); a[5] = (short)f2bf(a1.y);
        a[6] = (short)f2bf(a1.z); a[7] = (short)f2bf(a1.w);
        const bf16x8* bp = (const bf16x8*)(Bfrag + (size_t)ks * 64 * 8 + lane * 8);
        // nt stride in Bfrag = 4*64*8 shorts = 2048
        acc0 = __builtin_amdgcn_mfma_f32_16x16x32_bf16(a, bp[0 * 256], acc0, 0, 0, 0);
        acc1 = __builtin_amdgcn_mfma_f32_16x16x32_bf16(a, bp[1 * 256], acc1, 0, 0, 0);
        acc2 = __builtin_amdgcn_mfma_f32_16x16x32_bf16(a, bp[2 * 256], acc2, 0, 0, 0);
        acc3 = __builtin_amdgcn_mfma_f32_16x16x32_bf16(a, bp[3 * 256], acc3, 0, 0, 0);
    }

    // C/D: col = nt*16 + (lane&15), row = r0 + (lane>>4)*4 + j
    int c = lane & 15;
    int rbase = r0 + ((lane >> 4) << 2);
    #pragma unroll
    for (int j = 0; j < 4; j++) {
        int row = rbase + j;
        if (row < N) {
            float di = dinv[row];
            unsigned short* p = ppb + (size_t)row * 64 + c;
            p[0]  = f2bf(acc0[j] * di);
            p[16] = f2bf(acc1[j] * di);
            p[32] = f2bf(acc2[j] * di);
            p[48] = f2bf(acc3[j] * di);
        }
    }
}

// G: wave/node; 8 records per step = 4 independent half-wave gathers in flight.
__global__ void k_fused1(const int* __restrict__ offs, const int* __restrict__ csr,
                         const unsigned short* __restrict__ ppb,
                         const float* __restrict__ dinv, const float* __restrict__ b1,
                         const float* __restrict__ W2, float* __restrict__ qp, int N) {
    int t = blockIdx.x * blockDim.x + threadIdx.x;
    int lane = t & 63;
    int half = lane >> 5;
    int hl = lane & 31;
    int node = t >> 6;
    int nstride = (gridDim.x * blockDim.x) >> 6;
    float w2a = W2[2 * hl], w2b = W2[2 * hl + 1];
    float ba = b1[2 * hl], bb = b1[2 * hl + 1];
    for (; node < N; node += nstride) {
        int start = offs[node], end = offs[node + 1];
        float acca = 0.0f, accb = 0.0f;
        if (half == 0) {  // self-loop term counted once
            unsigned int v = *(const unsigned int*)&ppb[(size_t)node * 64 + 2 * hl];
            acca = bf2f((unsigned short)v);
            accb = bf2f((unsigned short)(v >> 16));
        }
        for (int j0 = start; j0 < end; j0 += 64) {
            int jj = j0 + lane;
            int idx = (jj < end) ? csr[jj] : 0;
            int m = end - j0; if (m > 64) m = 64;
            for (int kk = 0; kk < m; kk += 8) {   // 8 records, 4 loads in flight
                int sidx[4]; bool act[4];
                #pragma unroll
                for (int q = 0; q < 4; q++) {
                    int ka = kk + 2 * q, kb = ka + 1;
                    int kac = (ka < m) ? ka : m - 1;     // wave-uniform clamp
                    int kbc = (kb < m) ? kb : m - 1;
                    int s0 = __shfl(idx, kac, 64);       // full-exec shuffles
                    int s1 = __shfl(idx, kbc, 64);
                    sidx[q] = half ? s1 : s0;
                    act[q] = half ? (kb < m) : (ka < m);
                }
                unsigned int v[4];
                #pragma unroll
                for (int q = 0; q < 4; q++)
                    if (act[q]) v[q] = *(const unsigned int*)&ppb[(size_t)sidx[q] * 64 + 2 * hl];
                #pragma unroll
                for (int q = 0; q < 4; q++)
                    if (act[q]) {
                        acca += bf2f((unsigned short)(v[q] & 0xffffu));
                        accb += bf2f((unsigned short)(v[q] >> 16));
                    }
            }
        }
        acca += __shfl_xor(acca, 32, 64);
        accb += __shfl_xor(accb, 32, 64);
        float di = dinv[node];
        float ha = fmaxf(di * acca + ba, 0.0f);
        float hb = fmaxf(di * accb + bb, 0.0f);
        float v = ha * w2a + hb * w2b;
        #pragma unroll
        for (int mm = 16; mm > 0; mm >>= 1) v += __shfl_xor(v, mm, 64);
        if (lane == 0) qp[node] = v * di;
    }
}

// H: out = dinv*(qp[self] + sum qp[csr]) + b2
__global__ void k_fused2(const int* __restrict__ offs, const int* __restrict__ csr,
                         const float* __restrict__ qp, const float* __restrict__ dinv,
                         const float* __restrict__ b2, float* __restrict__ out, int N) {
    int i = blockIdx.x * blockDim.x + threadIdx.x;
    if (i < N) {
        int start = offs[i], end = offs[i + 1];
        float s = qp[i];
        for (int j = start; j < end; j++) s += qp[csr[j]];
        out[i] = dinv[i] * s + b2[0];
    }
}

extern "C" void kernel_launch(void* const* d_in, const int* in_sizes, int n_in,
                              void* d_out, int out_size, void* d_ws, size_t ws_size,
                              hipStream_t stream) {
    const float* x  = (const float*)d_in[0];
    const int*   ei = (const int*)d_in[1];
    const float* W1 = (const float*)d_in[2];
    const float* b1 = (const float*)d_in[3];
    const float* W2 = (const float*)d_in[4];
    const float* b2 = (const float*)d_in[5];
    float* out = (float*)d_out;

    int N = in_sizes[0] / 128;
    int E = in_sizes[1] / 2;
    const int* src = ei;
    const int* dst = ei + E;
    int NB = (N + 255) >> 8;
    int chunk = (E + NBLK - 1) / NBLK;

    size_t Np = ((size_t)N + 255) & ~(size_t)255;
    size_t Ep = ((size_t)E + 255) & ~(size_t)255;
    char* w = (char*)d_ws;
    int* bh      = (int*)w;            w += (size_t)NBLK * 512 * 4;
    int* btot    = (int*)w;            w += 512 * 4;
    int* bbase   = (int*)w;            w += 512 * 4;
    unsigned int* grouped = (unsigned int*)w;  w += Ep * 4;
    int* offs    = (int*)w;            w += (Np + 256) * 4;
    int* csr     = (int*)w;            w += Ep * 4;
    float* dinv  = (float*)w;          w += Np * 4;
    unsigned short* ppb = (unsigned short*)w;  w += Np * 64 * 2;
    float* qp    = (float*)w;          w += Np * 4;
    unsigned short* Bfrag = (unsigned short*)w;  /* 8192 ushorts */

    k_packB<<<1, 256, 0, stream>>>(W1, Bfrag);
    k_hist<<<NBLK, 256, 0, stream>>>(dst, E, chunk, NB, bh);
    k_bscan<<<NB, 256, 0, stream>>>(bh, NB, btot);
    k_cscan<<<1, 512, 0, stream>>>(btot, NB, E, bbase, offs, N);
    k_dscatter<<<NBLK, 256, 0, stream>>>(src, dst, E, chunk, bh, bbase, NB, grouped);
    k_bfill<<<NB, 256, 0, stream>>>(grouped, bbase, btot, N, offs, csr, dinv);
    k_gemm1m<<<(N + 63) / 64, 256, 0, stream>>>(x, Bfrag, dinv, ppb, N);
    k_fused1<<<2048, 256, 0, stream>>>(offs, csr, ppb, dinv, b1, W2, qp, N);
    k_fused2<<<(N + 255) / 256, 256, 0, stream>>>(offs, csr, qp, dinv, b2, out, N);
}

// Round 10
// 194.892 us; speedup vs baseline: 3.6657x; 1.0134x over previous
//
#include <hip/hip_runtime.h>

// 2-layer GCN. LDS-multisplit CSR build + bf16 MFMA gemm1 + quarter-wave fused1.
// Pipeline:
//  A k_hist     : per-block LDS hist over NB dst-buckets (bucket = dst>>8)
//  B k_bscan    : per-bucket exclusive scan over the 256 blocks
//  C k_cscan    : exclusive scan of bucket totals -> bucket bases; + packs W1
//                 into bf16 B-fragments (merged to save a launch)
//  D k_dscatter : scatter packed (src<<8|dst&255) into bucket-grouped array
//  E k_bfill    : per-bucket node hist+scan -> offs/dinv; csr via LDS staging
//  F k_gemm1m   : pp = (x@W1)*dinv[row] via v_mfma_f32_16x16x32_bf16, bf16 store
//  G k_fused1   : wave/node, quarter-wave per edge (NO shuffles in edge loop);
//                 h=relu(dinv*acc+b1); qp=(h.W2)*dinv
//  H k_fused2   : thread/node: out = dinv*(qp[self]+sum qp[csr]) + b2
//
// gfx950 NOTES: __shfl = ds_bpermute (source lane must be exec-active; all
// shuffles run full-exec with wave-uniform lane args). No per-edge LDS atomics
// (R6: 10x slower than register accumulation). MFMA 16x16x32 bf16 layouts:
// A row=l&15,k=(l>>4)*8+j; B col=l&15,k=(l>>4)*8+j; C/D col=lane&15,
// row=(lane>>4)*4+reg (m89-verified, confirmed by R8 absmax).

#define NBLK 256
#define MAXB 8192

typedef __attribute__((ext_vector_type(8))) short bf16x8;
typedef __attribute__((ext_vector_type(4))) float f32x4;

__device__ __forceinline__ float bf2f(unsigned short u) {
    union { unsigned int i; float f; } v; v.i = ((unsigned int)u) << 16; return v.f;
}
__device__ __forceinline__ unsigned short f2bf(float f) {
    union { float f; unsigned int i; } v; v.f = f;
    unsigned int r = (v.i + 0x7fffu + ((v.i >> 16) & 1u)) >> 16;
    return (unsigned short)r;
}

// A: per-block histogram of dst buckets
__global__ __launch_bounds__(256) void k_hist(const int* __restrict__ dst, int E, int chunk,
                                              int NB, int* __restrict__ bh) {
    __shared__ int h[512];
    int blk = blockIdx.x, t = threadIdx.x;
    h[t] = 0; h[t + 256] = 0;
    __syncthreads();
    int e0 = blk * chunk, e1 = min(E, e0 + chunk);
    for (int e = e0 + t; e < e1; e += 256) atomicAdd(&h[dst[e] >> 8], 1);
    __syncthreads();
    for (int k = t; k < NB; k += 256) bh[blk * NB + k] = h[k];
}

// B: per-bucket exclusive scan over NBLK block counts
__global__ __launch_bounds__(256) void k_bscan(int* __restrict__ bh, int NB,
                                               int* __restrict__ btot) {
    __shared__ int s[256];
    int k = blockIdx.x, t = threadIdx.x;
    int v = bh[t * NB + k];
    s[t] = v;
    __syncthreads();
    for (int off = 1; off < 256; off <<= 1) {
        int u = (t >= off) ? s[t - off] : 0;
        __syncthreads();
        s[t] += u;
        __syncthreads();
    }
    bh[t * NB + k] = s[t] - v;
    if (t == 255) btot[k] = s[255];
}

// C: exclusive scan of bucket totals (NB <= 512) + W1 -> Bfrag pack (merged)
__global__ __launch_bounds__(512) void k_cscan(const int* __restrict__ btot, int NB, int E,
                                               int* __restrict__ bbase, int* __restrict__ offs,
                                               int N, const float* __restrict__ W1,
                                               unsigned short* __restrict__ Bfrag) {
    __shared__ int s[512];
    int t = threadIdx.x;
    int v = (t < NB) ? btot[t] : 0;
    s[t] = v;
    __syncthreads();
    for (int off = 1; off < 512; off <<= 1) {
        int u = (t >= off) ? s[t - off] : 0;
        __syncthreads();
        s[t] += u;
        __syncthreads();
    }
    if (t < NB) bbase[t] = s[t] - v;
    if (t == 0) offs[N] = E;
    // independent: pack W1 into B-fragment order
    // Bfrag[((nt*4+ks)*64+lane)*8+j] = bf16(W1[(ks*32+(lane>>4)*8+j)*64 + nt*16+(lane&15)])
    for (int i = t; i < 8192; i += 512) {
        int j    = i & 7;
        int lane = (i >> 3) & 63;
        int ks   = (i >> 9) & 3;
        int nt   = i >> 11;
        int k = ks * 32 + ((lane >> 4) << 3) + j;
        int n = nt * 16 + (lane & 15);
        Bfrag[i] = f2bf(W1[k * 64 + n]);
    }
}

// D: scatter packed records into bucket-grouped order (LDS cursors)
__global__ __launch_bounds__(256) void k_dscatter(const int* __restrict__ src,
                                                  const int* __restrict__ dst, int E, int chunk,
                                                  const int* __restrict__ bh,
                                                  const int* __restrict__ bbase, int NB,
                                                  unsigned int* __restrict__ grouped) {
    __shared__ int cur[512];
    int blk = blockIdx.x, t = threadIdx.x;
    for (int k = t; k < NB; k += 256) cur[k] = bbase[k] + bh[blk * NB + k];
    __syncthreads();
    int e0 = blk * chunk, e1 = min(E, e0 + chunk);
    for (int e = e0 + t; e < e1; e += 256) {
        int d = dst[e];
        int pos = atomicAdd(&cur[d >> 8], 1);
        grouped[pos] = ((unsigned int)src[e] << 8) | (unsigned int)(d & 255);
    }
}

// E: per-bucket node hist/scan -> offs, dinv; csr fill via LDS staging
__global__ __launch_bounds__(256) void k_bfill(const unsigned int* __restrict__ grouped,
                                               const int* __restrict__ bbase,
                                               const int* __restrict__ btot, int N,
                                               int* __restrict__ offs, int* __restrict__ csr,
                                               float* __restrict__ dinv) {
    __shared__ int hist[256], pfx[256], cur[256];
    __shared__ int stage[MAXB];
    int k = blockIdx.x, t = threadIdx.x;
    int base = bbase[k], cnt = btot[k];
    hist[t] = 0;
    __syncthreads();
    for (int i = t; i < cnt; i += 256) atomicAdd(&hist[grouped[base + i] & 255u], 1);
    __syncthreads();
    int v = hist[t];
    pfx[t] = v;
    __syncthreads();
    for (int off = 1; off < 256; off <<= 1) {
        int u = (t >= off) ? pfx[t - off] : 0;
        __syncthreads();
        pfx[t] += u;
        __syncthreads();
    }
    int excl = pfx[t] - v;
    cur[t] = excl;
    int node = (k << 8) + t;
    if (node < N) {
        offs[node] = base + excl;
        dinv[node] = rsqrtf((float)v + 1.0f);
    }
    __syncthreads();
    if (cnt <= MAXB) {
        for (int i = t; i < cnt; i += 256) {
            unsigned int p = grouped[base + i];
            int pos = atomicAdd(&cur[p & 255u], 1);
            stage[pos] = (int)(p >> 8);
        }
        __syncthreads();
        for (int i = t; i < cnt; i += 256) csr[base + i] = stage[i];
    } else {
        for (int i = t; i < cnt; i += 256) {
            unsigned int p = grouped[base + i];
            int pos = atomicAdd(&cur[p & 255u], 1);
            csr[base + pos] = (int)(p >> 8);
        }
    }
}

// F: MFMA gemm1. Block = 4 waves x 16 rows = 64 rows, all 64 cols. No LDS.
__global__ __launch_bounds__(256) void k_gemm1m(
    const float* __restrict__ x, const unsigned short* __restrict__ Bfrag,
    const float* __restrict__ dinv, unsigned short* __restrict__ ppb, int N)
{
    int lane = threadIdx.x & 63;
    int wid = threadIdx.x >> 6;
    int r0 = blockIdx.x * 64 + wid * 16;
    int arow = r0 + (lane & 15);
    if (arow > N - 1) arow = N - 1;              // clamp (stores guarded)
    const float* xrow = x + (size_t)arow * 128 + ((lane >> 4) << 3);

    f32x4 acc0 = {0.f, 0.f, 0.f, 0.f};
    f32x4 acc1 = {0.f, 0.f, 0.f, 0.f};
    f32x4 acc2 = {0.f, 0.f, 0.f, 0.f};
    f32x4 acc3 = {0.f, 0.f, 0.f, 0.f};

    #pragma unroll
    for (int ks = 0; ks < 4; ks++) {
        float4 a0 = *(const float4*)(xrow + ks * 32);
        float4 a1 = *(const float4*)(xrow + ks * 32 + 4);
        bf16x8 a;
        a[0] = (short)f2bf(a0.x); a[1] = (short)f2bf(a0.y);
        a[2] = (short)f2bf(a0.z); a[3] = (short)f2bf(a0.w);
        a[4] = (short)f2bf(a1.x); a[5] = (short)f2bf(a1.y);
        a[6] = (short)f2bf(a1.z); a[7] = (short)f2bf(a1.w);
        const bf16x8* bp = (const bf16x8*)(Bfrag + (size_t)ks * 64 * 8 + lane * 8);
        acc0 = __builtin_amdgcn_mfma_f32_16x16x32_bf16(a, bp[0 * 256], acc0, 0, 0, 0);
        acc1 = __builtin_amdgcn_mfma_f32_16x16x32_bf16(a, bp[1 * 256], acc1, 0, 0, 0);
        acc2 = __builtin_amdgcn_mfma_f32_16x16x32_bf16(a, bp[2 * 256], acc2, 0, 0, 0);
        acc3 = __builtin_amdgcn_mfma_f32_16x16x32_bf16(a, bp[3 * 256], acc3, 0, 0, 0);
    }

    int c = lane & 15;
    int rbase = r0 + ((lane >> 4) << 2);
    #pragma unroll
    for (int j = 0; j < 4; j++) {
        int row = rbase + j;
        if (row < N) {
            float di = dinv[row];
            unsigned short* p = ppb + (size_t)row * 64 + c;
            p[0]  = f2bf(acc0[j] * di);
            p[16] = f2bf(acc1[j] * di);
            p[32] = f2bf(acc2[j] * di);
            p[48] = f2bf(acc3[j] * di);
        }
    }
}

// G: wave/node. lane = q*16+s; quarter q handles edge j0+q; lane owns cols
// [4s,4s+4). No shuffles in the edge loop; 2 gathers in flight (unroll x2).
__global__ void k_fused1(const int* __restrict__ offs, const int* __restrict__ csr,
                         const unsigned short* __restrict__ ppb,
                         const float* __restrict__ dinv, const float* __restrict__ b1,
                         const float* __restrict__ W2, float* __restrict__ qp, int N) {
    int t = blockIdx.x * blockDim.x + threadIdx.x;
    int lane = t & 63;
    int q = lane >> 4;         // quarter 0..3
    int s = lane & 15;         // col group: cols 4s..4s+3
    int node = t >> 6;
    int nstride = (gridDim.x * blockDim.x) >> 6;
    float w0 = W2[4 * s], w1 = W2[4 * s + 1], w2 = W2[4 * s + 2], w3 = W2[4 * s + 3];
    float bb0 = b1[4 * s], bb1 = b1[4 * s + 1], bb2 = b1[4 * s + 2], bb3 = b1[4 * s + 3];
    for (; node < N; node += nstride) {
        int start = offs[node], end = offs[node + 1];
        float a0 = 0.f, a1 = 0.f, a2 = 0.f, a3 = 0.f;
        if (q == 0) {   // self-loop term, counted once (quarter 0 only)
            uint2 v = *(const uint2*)&ppb[(size_t)node * 64 + 4 * s];
            a0 = bf2f((unsigned short)(v.x & 0xffffu));
            a1 = bf2f((unsigned short)(v.x >> 16));
            a2 = bf2f((unsigned short)(v.y & 0xffffu));
            a3 = bf2f((unsigned short)(v.y >> 16));
        }
        for (int j0 = start; j0 < end; j0 += 8) {   // 8 edges per iter (2/quarter)
            int ja = j0 + q, jb = j0 + 4 + q;
            bool aa = ja < end, ab = jb < end;
            int ia = csr[aa ? ja : end - 1];
            int ib = csr[ab ? jb : end - 1];
            uint2 va, vb;
            if (aa) va = *(const uint2*)&ppb[(size_t)ia * 64 + 4 * s];
            if (ab) vb = *(const uint2*)&ppb[(size_t)ib * 64 + 4 * s];
            if (aa) {
                a0 += bf2f((unsigned short)(va.x & 0xffffu));
                a1 += bf2f((unsigned short)(va.x >> 16));
                a2 += bf2f((unsigned short)(va.y & 0xffffu));
                a3 += bf2f((unsigned short)(va.y >> 16));
            }
            if (ab) {
                a0 += bf2f((unsigned short)(vb.x & 0xffffu));
                a1 += bf2f((unsigned short)(vb.x >> 16));
                a2 += bf2f((unsigned short)(vb.y & 0xffffu));
                a3 += bf2f((unsigned short)(vb.y >> 16));
            }
        }
        // reduce across quarters (all lanes active, full-exec shuffles)
        a0 += __shfl_xor(a0, 16, 64); a1 += __shfl_xor(a1, 16, 64);
        a2 += __shfl_xor(a2, 16, 64); a3 += __shfl_xor(a3, 16, 64);
        a0 += __shfl_xor(a0, 32, 64); a1 += __shfl_xor(a1, 32, 64);
        a2 += __shfl_xor(a2, 32, 64); a3 += __shfl_xor(a3, 32, 64);
        float di = dinv[node];
        float h0 = fmaxf(di * a0 + bb0, 0.f);
        float h1 = fmaxf(di * a1 + bb1, 0.f);
        float h2 = fmaxf(di * a2 + bb2, 0.f);
        float h3 = fmaxf(di * a3 + bb3, 0.f);
        float v = h0 * w0 + h1 * w1 + h2 * w2 + h3 * w3;
        #pragma unroll
        for (int m = 8; m > 0; m >>= 1) v += __shfl_xor(v, m, 64);
        if (lane == 0) qp[node] = v * di;
    }
}

// H: out = dinv*(qp[self] + sum qp[csr]) + b2
__global__ void k_fused2(const int* __restrict__ offs, const int* __restrict__ csr,
                         const float* __restrict__ qp, const float* __restrict__ dinv,
                         const float* __restrict__ b2, float* __restrict__ out, int N) {
    int i = blockIdx.x * blockDim.x + threadIdx.x;
    if (i < N) {
        int start = offs[i], end = offs[i + 1];
        float s = qp[i];
        for (int j = start; j < end; j++) s += qp[csr[j]];
        out[i] = dinv[i] * s + b2[0];
    }
}

extern "C" void kernel_launch(void* const* d_in, const int* in_sizes, int n_in,
                              void* d_out, int out_size, void* d_ws, size_t ws_size,
                              hipStream_t stream) {
    const float* x  = (const float*)d_in[0];
    const int*   ei = (const int*)d_in[1];
    const float* W1 = (const float*)d_in[2];
    const float* b1 = (const float*)d_in[3];
    const float* W2 = (const float*)d_in[4];
    const float* b2 = (const float*)d_in[5];
    float* out = (float*)d_out;

    int N = in_sizes[0] / 128;
    int E = in_sizes[1] / 2;
    const int* src = ei;
    const int* dst = ei + E;
    int NB = (N + 255) >> 8;
    int chunk = (E + NBLK - 1) / NBLK;

    size_t Np = ((size_t)N + 255) & ~(size_t)255;
    size_t Ep = ((size_t)E + 255) & ~(size_t)255;
    char* w = (char*)d_ws;
    int* bh      = (int*)w;            w += (size_t)NBLK * 512 * 4;
    int* btot    = (int*)w;            w += 512 * 4;
    int* bbase   = (int*)w;            w += 512 * 4;
    unsigned int* grouped = (unsigned int*)w;  w += Ep * 4;
    int* offs    = (int*)w;            w += (Np + 256) * 4;
    int* csr     = (int*)w;            w += Ep * 4;
    float* dinv  = (float*)w;          w += Np * 4;
    unsigned short* ppb = (unsigned short*)w;  w += Np * 64 * 2;
    float* qp    = (float*)w;          w += Np * 4;
    unsigned short* Bfrag = (unsigned short*)w;  /* 8192 ushorts */

    k_hist<<<NBLK, 256, 0, stream>>>(dst, E, chunk, NB, bh);
    k_bscan<<<NB, 256, 0, stream>>>(bh, NB, btot);
    k_cscan<<<1, 512, 0, stream>>>(btot, NB, E, bbase, offs, N, W1, Bfrag);
    k_dscatter<<<NBLK, 256, 0, stream>>>(src, dst, E, chunk, bh, bbase, NB, grouped);
    k_bfill<<<NB, 256, 0, stream>>>(grouped, bbase, btot, N, offs, csr, dinv);
    k_gemm1m<<<(N + 63) / 64, 256, 0, stream>>>(x, Bfrag, dinv, ppb, N);
    k_fused1<<<2048, 256, 0, stream>>>(offs, csr, ppb, dinv, b1, W2, qp, N);
    k_fused2<<<(N + 255) / 256, 256, 0, stream>>>(offs, csr, qp, dinv, b2, out, N);
}